// Round 10
// baseline (358.110 us; speedup 1.0000x reference)
//
#include <hip/hip_runtime.h>

// C3-style layer, R9: two-pass, LDS-free, barrier-free MFMA conv.
// x[32,6,512,512] f32 -> out[32,16,508,508] f32 (5x5 VALID conv; sparse
// oc<-ic connectivity via zero weights in dense [16,6,5,5] kernel).
//
// Pass 1: pack x into xh[bz][gy][gx][icp8] f16 (d_ws, 134 MB).
// Pass 2: wave = 32 px x 4 output rows. B-fragment for (row-slot, kx) is a
// single 16-B global load from xh (coalesced 1 KB/wave-instr, L2-band-reuse).
// Per kx: 4 loads feed 6 MFMAs across two independent chains (rows Y..Y+1,
// Y+2..Y+3). No __shared__, no __syncthreads -> no barrier drains; latency
// hidden by 2-chain ILP + TLP.  A-frag/C layouts verbatim from R6 (verified).

#define OW 508

typedef _Float16 h8 __attribute__((ext_vector_type(8)));
typedef float f32x16 __attribute__((ext_vector_type(16)));

__device__ __constant__ int d_CH3[6][3] = {
    {0,1,2},{1,2,3},{2,3,4},{3,4,5},{0,4,5},{0,1,5}};
__device__ __constant__ int d_CH4[9][4] = {
    {0,1,2,3},{1,2,3,4},{2,3,4,5},{0,3,4,5},{0,1,4,5},
    {0,1,2,5},{0,1,3,4},{1,2,4,5},{0,2,3,5}};

// ws: bias f32[16] @0 | AF ushort[15*64*8] @64B | xh h8[32*512*512] @16KB
// AF[((kx*3+ch)*64 + lane)*8 + e]: A-frag: oc=lane&15, dy=(lane>>4)&1,
// rr=lane>>5, ky=ch*2+rr-dy; value W[oc][e][ky][kx] or 0.  (verified R6)
__global__ void prep_weights(const float* __restrict__ w3, const float* __restrict__ b3,
                             const float* __restrict__ w4, const float* __restrict__ b4,
                             const float* __restrict__ w6, const float* __restrict__ b6,
                             float* __restrict__ bias, unsigned short* __restrict__ AF) {
    __shared__ float Wfull[16 * 6 * 25];   // dense [oc][ic][tap]
    const int tid = threadIdx.x;
    for (int i = tid; i < 16 * 6 * 25; i += 256) Wfull[i] = 0.f;
    __syncthreads();
    for (int i = tid; i < 6 * 3 * 25; i += 256) {
        int oc = i / 75, r = i % 75, c = r / 25, t = r % 25;
        Wfull[(oc * 6 + d_CH3[oc][c]) * 25 + t] = w3[i];
    }
    for (int i = tid; i < 9 * 4 * 25; i += 256) {
        int o = i / 100, r = i % 100, c = r / 25, t = r % 25;
        Wfull[((6 + o) * 6 + d_CH4[o][c]) * 25 + t] = w4[i];
    }
    for (int i = tid; i < 6 * 25; i += 256) Wfull[15 * 150 + i] = w6[i];
    __syncthreads();
    for (int i = tid; i < 15 * 64 * 8; i += 256) {
        int e = i & 7, lane = (i >> 3) & 63, q = i >> 9;   // q = kx*3+ch
        int kx = q / 3, ch = q % 3;
        int oc = lane & 15, dy = (lane >> 4) & 1, rr = lane >> 5;
        int ky = ch * 2 + rr - dy;
        float w = 0.f;
        if (e < 6 && ky >= 0 && ky <= 4) w = Wfull[(oc * 6 + e) * 25 + ky * 5 + kx];
        _Float16 hw = (_Float16)w;
        AF[i] = __builtin_bit_cast(unsigned short, hw);
    }
    if (tid < 6)        bias[tid] = b3[tid];
    else if (tid < 15)  bias[tid] = b4[tid - 6];
    else if (tid == 15) bias[tid] = b6[0];
}

// Pass 1: f32 planar -> f16 icp8-packed. grid (512 rows, 32 bz), 256 thr (2 cols each).
__global__ __launch_bounds__(256) void pack_input(
        const float* __restrict__ x, h8* __restrict__ xh) {
    const int gy = blockIdx.x;
    const int bz = blockIdx.y;
    const int c0 = threadIdx.x * 2;
    const float* xb = x + (size_t)bz * (6 * 512 * 512) + (size_t)gy * 512 + c0;
    float2 v[6];
    #pragma unroll
    for (int ic = 0; ic < 6; ++ic)
        v[ic] = *(const float2*)(xb + (size_t)ic * 262144);
    h8 a, b;
    #pragma unroll
    for (int ic = 0; ic < 6; ++ic) {
        a[ic] = (_Float16)v[ic].x;
        b[ic] = (_Float16)v[ic].y;
    }
    a[6] = a[7] = (_Float16)0.f;
    b[6] = b[7] = (_Float16)0.f;
    h8* dst = xh + ((size_t)bz * 512 + gy) * 512 + c0;
    dst[0] = a;
    dst[1] = b;
}

// Pass 2: grid (16 x-strips, 32 y-groups, 32 bz), 256 thr = 4 waves.
// Wave wv covers output rows Y = yg*16 + wv*4 .. Y+3, px = xs*32 .. +31.
__global__ __launch_bounds__(256, 2) void conv_mfma(
        const h8* __restrict__ xh, const unsigned short* __restrict__ AF,
        const float* __restrict__ bias, float* __restrict__ out) {
    const int tid  = threadIdx.x;
    const int lane = tid & 63;
    const int wv   = tid >> 6;
    const int Y    = blockIdx.y * 16 + wv * 4;
    if (Y >= OW) return;                     // only (yg=31, wv=3); Y<=504 after this
    const int n  = lane & 31;
    const int h  = lane >> 5;
    const int px = blockIdx.x * 32 + n;
    const int pxl = px < OW ? px : OW - 1;   // clamp loads; clamped lanes never stored
    const int bz = blockIdx.z;

    // A-fragments: 15 x 16 B per lane, coalesced, L2-resident
    h8 afr[15];
    #pragma unroll
    for (int q = 0; q < 15; ++q)
        afr[q] = *reinterpret_cast<const h8*>(AF + (q * 64 + lane) * 8);

    // bias per acc reg r (r&7 pattern): ocb = (r&3) + 8*((r>>2)&1), oc = ocb + 4h
    float bv[8];
    #pragma unroll
    for (int r = 0; r < 8; ++r)
        bv[r] = bias[(r & 3) + 8 * (r >> 2) + 4 * h];

    f32x16 acc0, acc1;
    #pragma unroll
    for (int r = 0; r < 16; ++r) { acc0[r] = bv[r & 7]; acc1[r] = bv[r & 7]; }

    // B base: row Y+h, col pxl.  Slot o (0,2,4,6): +o*512.  Tap kx: +kx.
    const h8* xr = xh + ((size_t)bz * 512 + (Y + h)) * 512 + pxl;

    #pragma unroll
    for (int kx = 0; kx < 5; ++kx) {
        h8 b0 = xr[kx];
        h8 b1 = xr[kx + 2 * 512];
        h8 b2 = xr[kx + 4 * 512];
        h8 b3 = xr[kx + 6 * 512];
        // chain0 = rows Y,Y+1 (slots +0,+2,+4); chain1 = rows Y+2,Y+3 (+2,+4,+6)
        acc0 = __builtin_amdgcn_mfma_f32_32x32x16_f16(afr[3 * kx + 0], b0, acc0, 0, 0, 0);
        acc1 = __builtin_amdgcn_mfma_f32_32x32x16_f16(afr[3 * kx + 0], b1, acc1, 0, 0, 0);
        acc0 = __builtin_amdgcn_mfma_f32_32x32x16_f16(afr[3 * kx + 1], b1, acc0, 0, 0, 0);
        acc1 = __builtin_amdgcn_mfma_f32_32x32x16_f16(afr[3 * kx + 1], b2, acc1, 0, 0, 0);
        acc0 = __builtin_amdgcn_mfma_f32_32x32x16_f16(afr[3 * kx + 2], b2, acc0, 0, 0, 0);
        acc1 = __builtin_amdgcn_mfma_f32_32x32x16_f16(afr[3 * kx + 2], b3, acc1, 0, 0, 0);
    }

    // stores: oy = Y + 2*chain + dy <= 507 always (Y<=504)
    if (px < OW) {
        const size_t cs = (size_t)OW * OW;
        float* ob = out + ((size_t)bz * 16 + 4 * h) * cs + px;
        #pragma unroll
        for (int dy = 0; dy < 2; ++dy) {
            #pragma unroll
            for (int r8 = 0; r8 < 8; ++r8) {
                const int reg = dy * 8 + r8;
                const int ocb = (r8 & 3) + 8 * (r8 >> 2);
                ob[(size_t)ocb * cs + (size_t)(Y + dy) * OW]     = acc0[reg];
                ob[(size_t)ocb * cs + (size_t)(Y + 2 + dy) * OW] = acc1[reg];
            }
        }
    }
}

extern "C" void kernel_launch(void* const* d_in, const int* in_sizes, int n_in,
                              void* d_out, int out_size, void* d_ws, size_t ws_size,
                              hipStream_t stream) {
    const float* x  = (const float*)d_in[0];
    const float* w3 = (const float*)d_in[1];
    const float* b3 = (const float*)d_in[2];
    const float* w4 = (const float*)d_in[3];
    const float* b4 = (const float*)d_in[4];
    const float* w6 = (const float*)d_in[5];
    const float* b6 = (const float*)d_in[6];
    float* out = (float*)d_out;

    float* bias        = (float*)d_ws;                        // 16 f32 @ 0
    unsigned short* AF = (unsigned short*)d_ws + 32;          // 7680 u16 @ 64 B
    h8* xh             = (h8*)((char*)d_ws + 16384);          // 32*512*512*16 B

    prep_weights<<<1, 256, 0, stream>>>(w3, b3, w4, b4, w6, b6, bias, AF);

    dim3 grid1(512, 32);
    pack_input<<<grid1, 256, 0, stream>>>(x, xh);

    dim3 grid2(16, 32, 32);
    conv_mfma<<<grid2, 256, 0, stream>>>(xh, AF, bias, out);
}

// Round 11
// 257.421 us; speedup vs baseline: 1.3911x; 1.3911x over previous
//
#include <hip/hip_runtime.h>

// C3-style layer via MFMA implicit GEMM, R10: R6/R8-verified 32x32x16 compute
// in a minimal-LDS (22.8 KB -> 6-7 blocks/CU), single-barrier tile.
// x[32,6,512,512] f32 -> out[32,16,508,508] f32 (5x5 VALID conv; sparse
// oc<-ic connectivity via zero weights in dense [16,6,5,5] kernel).
//
// GEMM per kx: K=(window_row, icp8), M=32=(2 output rows x 16 oc), N=32 px.
// A-frags d-independent (prep kernel, verified R6).  Block = 64 px x 16 rows;
// 4 waves = 2 px-strips x 2 d-halves (verified R8 assignment).  Theory: all
// prior variants (267-305us) were latency-bound with every pipe <35% busy and
// occupancy capped at ~12 waves/CU by LDS/grid -- this tile lifts it to ~24+.

#define OW 508
#define BX 64     // output px per block; 2 strips x 32
#define BY 16     // output rows per block
#define TC 68     // staged columns = BX + 4
#define TR 21     // uint4 slots per column (20 rows; odd pitch spreads banks)

typedef _Float16 h8 __attribute__((ext_vector_type(8)));
typedef _Float16 h2 __attribute__((ext_vector_type(2)));
typedef float f32x16 __attribute__((ext_vector_type(16)));

__device__ __constant__ int d_CH3[6][3] = {
    {0,1,2},{1,2,3},{2,3,4},{3,4,5},{0,4,5},{0,1,5}};
__device__ __constant__ int d_CH4[9][4] = {
    {0,1,2,3},{1,2,3,4},{2,3,4,5},{0,3,4,5},{0,1,4,5},
    {0,1,2,5},{0,1,3,4},{1,2,4,5},{0,2,3,5}};

// ws: bias f32[16] | AF ushort[15*64*8]
// AF[((kx*3+ch)*64 + lane)*8 + e]: A-frag: oc=lane&15, dy=(lane>>4)&1,
// rr=lane>>5, ky=ch*2+rr-dy; value W[oc][e][ky][kx] or 0.  (verified R6)
__global__ void prep_weights(const float* __restrict__ w3, const float* __restrict__ b3,
                             const float* __restrict__ w4, const float* __restrict__ b4,
                             const float* __restrict__ w6, const float* __restrict__ b6,
                             float* __restrict__ bias, unsigned short* __restrict__ AF) {
    __shared__ float Wfull[16 * 6 * 25];   // dense [oc][ic][tap]
    const int tid = threadIdx.x;
    for (int i = tid; i < 16 * 6 * 25; i += 256) Wfull[i] = 0.f;
    __syncthreads();
    for (int i = tid; i < 6 * 3 * 25; i += 256) {
        int oc = i / 75, r = i % 75, c = r / 25, t = r % 25;
        Wfull[(oc * 6 + d_CH3[oc][c]) * 25 + t] = w3[i];
    }
    for (int i = tid; i < 9 * 4 * 25; i += 256) {
        int o = i / 100, r = i % 100, c = r / 25, t = r % 25;
        Wfull[((6 + o) * 6 + d_CH4[o][c]) * 25 + t] = w4[i];
    }
    for (int i = tid; i < 6 * 25; i += 256) Wfull[15 * 150 + i] = w6[i];
    __syncthreads();
    for (int i = tid; i < 15 * 64 * 8; i += 256) {
        int e = i & 7, lane = (i >> 3) & 63, q = i >> 9;   // q = kx*3+ch
        int kx = q / 3, ch = q % 3;
        int oc = lane & 15, dy = (lane >> 4) & 1, rr = lane >> 5;
        int ky = ch * 2 + rr - dy;
        float w = 0.f;
        if (e < 6 && ky >= 0 && ky <= 4) w = Wfull[(oc * 6 + e) * 25 + ky * 5 + kx];
        _Float16 hw = (_Float16)w;
        AF[i] = __builtin_bit_cast(unsigned short, hw);
    }
    if (tid < 6)        bias[tid] = b3[tid];
    else if (tid < 15)  bias[tid] = b4[tid - 6];
    else if (tid == 15) bias[tid] = b6[0];
}

__global__ __launch_bounds__(256, 4) void conv_mfma(
        const float* __restrict__ x, const unsigned short* __restrict__ AF,
        const float* __restrict__ bias, float* __restrict__ out) {
    __shared__ uint4 T4[TC * TR];   // 22848 B -> 6-7 blocks/CU

    const int tid = threadIdx.x;
    const int gx0 = blockIdx.x * BX;
    const int oy0 = blockIdx.y * BY;
    const int bz  = blockIdx.z;
    const float* xb = x + (size_t)bz * 6 * 512 * 512;
    unsigned int* Tw = (unsigned int*)T4;

    const int lane = tid & 63;
    const int h = lane >> 5;            // K-half / oc-half (verified R6 mapping)

    // global loads issued before the barrier -> overlap with LDS staging
    h8 afr[15];
    #pragma unroll
    for (int q = 0; q < 15; ++q)
        afr[q] = *reinterpret_cast<const h8*>(AF + (q * 64 + lane) * 8);

    f32x16 binit;
    #pragma unroll
    for (int reg = 0; reg < 16; ++reg)
        binit[reg] = bias[((reg & 3) + 8 * ((reg >> 2) & 1) + 4 * h) & 15];

    // -- zero the never-staged ip=3 words (icp 6,7); disjoint from stage writes
    for (int i = tid; i < TC * TR; i += 256) Tw[i * 4 + 3] = 0u;

    // -- stage rows 0..19, ic-pairs 0..2, col-pairs 0..33 (zero outside image)
    for (int idx = tid; idx < 34 * 3 * 20; idx += 256) {
        int cp = idx % 34;
        int ip = (idx / 34) % 3;
        int rr = idx / 102;
        int gy = oy0 + rr;
        int c = 2 * cp, gx = gx0 + c;
        float2 a = {0.f, 0.f}, b = {0.f, 0.f};
        if (gy < 512 && gx < 512) {     // gx even -> gx<=510, float2 in-row safe
            a = *(const float2*)(xb + ((size_t)(2 * ip) * 512 + gy) * 512 + gx);
            b = *(const float2*)(xb + ((size_t)(2 * ip + 1) * 512 + gy) * 512 + gx);
        }
        h2 w0; w0.x = (_Float16)a.x; w0.y = (_Float16)b.x;
        h2 w1; w1.x = (_Float16)a.y; w1.y = (_Float16)b.y;
        int q0 = c * TR + rr;
        Tw[q0 * 4 + ip]        = __builtin_bit_cast(unsigned int, w0);
        Tw[(q0 + TR) * 4 + ip] = __builtin_bit_cast(unsigned int, w1);
    }
    __syncthreads();                    // the ONLY barrier

    const int wv = tid >> 6;
    const int s  = wv & 1;              // px strip
    const int dh = wv >> 1;             // d half
    const int colb = s * 32 + (lane & 31);
    const int px = gx0 + colb;
    const bool pxok = (px < OW);
    const size_t cs = (size_t)OW * OW;
    float* ob = out + ((size_t)bz * 16 + 4 * h) * cs + px;

    #pragma unroll 1
    for (int dd = 0; dd < 8; dd += 2) {
        const int d = dh * 8 + dd;      // output row pair (d, d+1)
        f32x16 acc = binit;
        #pragma unroll
        for (int kx = 0; kx < 5; ++kx) {
            const uint4* cb = &T4[(colb + kx) * TR + d + h];
            #pragma unroll
            for (int ch = 0; ch < 3; ++ch) {
                h8 bfr = *reinterpret_cast<const h8*>(&cb[2 * ch]);
                acc = __builtin_amdgcn_mfma_f32_32x32x16_f16(afr[kx * 3 + ch], bfr, acc, 0, 0, 0);
            }
        }
        #pragma unroll
        for (int dy = 0; dy < 2; ++dy) {
            const int oy = oy0 + d + dy;
            if (oy < OW && pxok) {
                #pragma unroll
                for (int r8 = 0; r8 < 8; ++r8) {
                    const int reg = dy * 8 + r8;
                    const int ocb = (r8 & 3) + 8 * (r8 >> 2);
                    ob[(size_t)ocb * cs + (size_t)oy * OW] = acc[reg];
                }
            }
        }
    }
}

extern "C" void kernel_launch(void* const* d_in, const int* in_sizes, int n_in,
                              void* d_out, int out_size, void* d_ws, size_t ws_size,
                              hipStream_t stream) {
    const float* x  = (const float*)d_in[0];
    const float* w3 = (const float*)d_in[1];
    const float* b3 = (const float*)d_in[2];
    const float* w4 = (const float*)d_in[3];
    const float* b4 = (const float*)d_in[4];
    const float* w6 = (const float*)d_in[5];
    const float* b6 = (const float*)d_in[6];
    float* out = (float*)d_out;

    float* bias        = (float*)d_ws;                    // 16 f32
    unsigned short* AF = (unsigned short*)(bias + 16);    // 7680 u16

    prep_weights<<<1, 256, 0, stream>>>(w3, b3, w4, b4, w6, b6, bias, AF);

    dim3 grid((OW + BX - 1) / BX, (OW + BY - 1) / BY, 32);  // 8, 32, 32
    conv_mfma<<<grid, 256, 0, stream>>>(x, AF, bias, out);
}